// Round 2
// baseline (271.467 us; speedup 1.0000x reference)
//
#include <hip/hip_runtime.h>

// Predictive-coding graph message passing, MI355X — round 2.
// Strategy: node state transposed to [N][B] (B=32). Each scatter pass is split
// into (a) a binning kernel that routes edges to 256 node-tiles (16 nodes each)
// via LDS-staged counting + global cursor reservation, and (b) an accumulate
// kernel where each tile is EXCLUSIVELY owned by one block accumulating in LDS
// (ds_add_f32) — zero global atomics on the hot accumulator (R1 showed global
// f32 atomics cost 65 MB of fabric traffic at ~1.2 TB/s = 55 us/pass).

static constexpr int kB = 32, kLogB = 5;
static constexpr int kTileNodes = 16;   // nodes per tile/bin
static constexpr int kNumBins = 256;    // N / kTileNodes (N = 4096)
static constexpr int kCap = 2560;       // slots/bin: mean 2048, +11 sigma slack
static constexpr int kChunk = 2048;     // edges per k_bin block

// K1: LDS-tiled transpose x[b*N+n] -> x_t[n*32+b]; fx_t = tanh(x); zero cursors.
__global__ void __launch_bounds__(256) k_init(
    const float* __restrict__ x, float* __restrict__ x_t,
    float* __restrict__ fx_t, int* __restrict__ cursA, int* __restrict__ cursB,
    int N) {
  __shared__ float tile[32][65];
  int tid = threadIdx.x;
  int n0 = blockIdx.x * 64;
  if (blockIdx.x == 0 && tid < kNumBins) { cursA[tid] = 0; cursB[tid] = 0; }
  for (int k = tid; k < 32 * 64; k += 256) {          // coalesced 256B rows
    int b = k >> 6, n = k & 63;
    tile[b][n] = x[b * N + n0 + n];
  }
  __syncthreads();
  for (int k = tid; k < 64 * 32; k += 256) {          // coalesced t-layout write
    int n = k >> 5, b = k & 31;
    float xv = tile[b][n];
    int j = (n0 + n) * kB + b;
    x_t[j] = xv;
    fx_t[j] = tanhf(xv);
  }
}

// K2/K4: route edges into per-tile bins. record = {meta=(other<<8)|local, w}.
__global__ void __launch_bounds__(256) k_bin(
    const int* __restrict__ key, const int* __restrict__ other,
    const float* __restrict__ w, uint2* __restrict__ bins,
    int* __restrict__ cursors, int E) {
  __shared__ int hist[kNumBins];
  __shared__ int base[kNumBins];
  __shared__ unsigned short lkey[kChunk];
  __shared__ unsigned short loff[kChunk];
  int tid = threadIdx.x;
  int e0 = blockIdx.x * kChunk;
  int nloc = min(kChunk, E - e0);
  if (tid < kNumBins) hist[tid] = 0;
  __syncthreads();
  for (int k = tid; k < nloc; k += 256) {
    int kk = key[e0 + k];
    lkey[k] = (unsigned short)kk;
    loff[k] = (unsigned short)atomicAdd(&hist[kk >> 4], 1);
  }
  __syncthreads();
  if (tid < kNumBins) base[tid] = atomicAdd(&cursors[tid], hist[tid]);
  __syncthreads();
  for (int k = tid; k < nloc; k += 256) {
    int kk = lkey[k];
    int bin = kk >> 4;
    int pos = base[bin] + loff[k];
    if (pos < kCap) {   // capacity guard (statistically never hit)
      unsigned meta = ((unsigned)other[e0 + k] << 8) | (unsigned)(kk & 15);
      bins[(size_t)bin * kCap + pos] = make_uint2(meta, __float_as_uint(w[e0 + k]));
    }
  }
}

// K3/K5: one block owns one tile; LDS accumulate; fused epilogue.
// mode 0: out=mu (batch-major), eps_t = x_t - mu.   mode 1: out=dx.
__global__ void __launch_bounds__(1024) k_accum(
    const uint2* __restrict__ bins, const int* __restrict__ cursors,
    const float* __restrict__ vals, const float* __restrict__ x_t,
    const float* __restrict__ fx_t, float* __restrict__ eps_t,
    float* __restrict__ out, int N, int mode) {
  __shared__ float acc[kTileNodes * 33];   // pad 33: conflict-free both phases
  int tid = threadIdx.x;
  if (tid < kTileNodes * 33) acc[tid] = 0.0f;
  __syncthreads();
  int t = blockIdx.x;
  int count = min(cursors[t], kCap);
  const uint2* bp = bins + (size_t)t * kCap;
  int b = tid & 31;
  int slot = tid >> 5;                     // 32 record-slots (1024 threads)
  const int nslot = blockDim.x >> 5;
  int i = slot;
  uint2 r = (i < count) ? bp[i] : make_uint2(0u, 0u);
  while (i < count) {                      // 1-deep record prefetch for MLP
    int inext = i + nslot;
    uint2 rn = (inext < count) ? bp[inext] : make_uint2(0u, 0u);
    float v = vals[((r.x >> 8) << kLogB) + b];      // 128B line per half-wave
    atomicAdd(&acc[(r.x & 255) * 33 + b], __uint_as_float(r.y) * v);  // ds_add
    r = rn;
    i = inext;
  }
  __syncthreads();
  int n0 = t * kTileNodes;
  for (int k = tid; k < kTileNodes * kB; k += blockDim.x) {
    int local = k >> 5, bb = k & 31;       // b-fast: eps_t write coalesced
    float s = acc[local * 33 + bb];
    int n = n0 + local;
    int j = n * kB + bb;
    if (mode == 0) {
      eps_t[j] = x_t[j] - s;
      out[bb * N + n] = s;                 // mu, scattered 4B (1MB total, L2)
    } else {
      float fx = fx_t[j];
      out[bb * N + n] = fmaf(1.0f - fx * fx, s, -eps_t[j]);   // dx
    }
  }
}

extern "C" void kernel_launch(void* const* d_in, const int* in_sizes, int n_in,
                              void* d_out, int out_size, void* d_ws, size_t ws_size,
                              hipStream_t stream) {
  const float* x    = (const float*)d_in[0];
  const float* w    = (const float*)d_in[1];
  const int*   esrc = (const int*)d_in[2];
  const int*   edst = (const int*)d_in[3];

  const int BN = in_sizes[0];          // 131072
  const int E  = in_sizes[1];          // 524288
  const int N  = BN / kB;              // 4096

  float* ws    = (float*)d_ws;
  float* x_t   = ws;                   // [BN]
  float* fx_t  = ws + (size_t)BN;      // [BN]
  float* eps_t = ws + 2 * (size_t)BN;  // [BN]
  int*   cursA = (int*)(ws + 3 * (size_t)BN);
  int*   cursB = cursA + kNumBins;
  uint2* bins  = (uint2*)(cursB + kNumBins);   // [256 * 2560] = 5.25 MB

  float* out_mu = (float*)d_out;
  float* out_dx = (float*)d_out + BN;

  int nblk_bin = (E + kChunk - 1) / kChunk;    // 256

  k_init<<<N / 64, 256, 0, stream>>>(x, x_t, fx_t, cursA, cursB, N);
  // Pass 1: mu[dst] += w * fx[src]  — bin by dst, gather fx at src.
  k_bin<<<nblk_bin, 256, 0, stream>>>(edst, esrc, w, bins, cursA, E);
  k_accum<<<kNumBins, 1024, 0, stream>>>(bins, cursA, fx_t, x_t, fx_t, eps_t,
                                         out_mu, N, 0);
  // Pass 2: dx_acc[src] += w * eps[dst] — bin by src, gather eps at dst.
  k_bin<<<nblk_bin, 256, 0, stream>>>(esrc, edst, w, bins, cursB, E);
  k_accum<<<kNumBins, 1024, 0, stream>>>(bins, cursB, eps_t, x_t, fx_t, eps_t,
                                         out_dx, N, 1);
}

// Round 3
// 145.946 us; speedup vs baseline: 1.8600x; 1.8600x over previous
//
#include <hip/hip_runtime.h>

// Predictive-coding graph message passing, MI355X — round 3.
// R2 lesson: atomicAdd(float*) on LDS lowers to a CAS retry loop -> 92us/pass
// of pure serialization. R3: each half-wave (record slot) owns a PRIVATE LDS
// accumulator replica (32 x 16 x 32 f32 = 64 KB) -> plain ds_read/fma/ds_write,
// zero atomics on the hot path; 32-replica tree-sum in the epilogue.

static constexpr int kB = 32, kLogB = 5;
static constexpr int kTileNodes = 16;   // nodes per tile/bin
static constexpr int kNumBins = 256;    // N / kTileNodes (N = 4096)
static constexpr int kCap = 2560;       // slots/bin: mean 2048, +11 sigma slack
static constexpr int kChunk = 2048;     // edges per binning block

// K1: LDS-tiled transpose x[b*N+n] -> x_t[n*32+b]; fx_t = tanh(x); zero cursors.
__global__ void __launch_bounds__(256) k_init(
    const float* __restrict__ x, float* __restrict__ x_t,
    float* __restrict__ fx_t, int* __restrict__ cursA, int* __restrict__ cursB,
    int N) {
  __shared__ float tile[32][65];
  int tid = threadIdx.x;
  int n0 = blockIdx.x * 64;
  if (blockIdx.x == 0 && tid < kNumBins) { cursA[tid] = 0; cursB[tid] = 0; }
  for (int k = tid; k < 32 * 64; k += 256) {
    int b = k >> 6, n = k & 63;
    tile[b][n] = x[b * N + n0 + n];
  }
  __syncthreads();
  for (int k = tid; k < 64 * 32; k += 256) {
    int n = k >> 5, b = k & 31;
    float xv = tile[b][n];
    int j = (n0 + n) * kB + b;
    x_t[j] = xv;
    fx_t[j] = tanhf(xv);
  }
}

// K2 (dual): one read of (esrc, edst, w); route into binsA (keyed by dst,
// payload src) and binsB (keyed by src, payload dst). Record = {meta,w}.
__global__ void __launch_bounds__(256) k_bin_dual(
    const int* __restrict__ esrc, const int* __restrict__ edst,
    const float* __restrict__ w, uint2* __restrict__ binsA,
    uint2* __restrict__ binsB, int* __restrict__ cursA,
    int* __restrict__ cursB, int E) {
  __shared__ int histA[kNumBins], histB[kNumBins];
  __shared__ int baseA[kNumBins], baseB[kNumBins];
  __shared__ unsigned short lsrc[kChunk], ldst[kChunk];
  __shared__ unsigned short loffA[kChunk], loffB[kChunk];
  int tid = threadIdx.x;
  int e0 = blockIdx.x * kChunk;
  int nloc = min(kChunk, E - e0);
  if (tid < kNumBins) { histA[tid] = 0; histB[tid] = 0; }
  __syncthreads();
  for (int k = tid; k < nloc; k += 256) {
    int s = esrc[e0 + k], d = edst[e0 + k];
    lsrc[k] = (unsigned short)s;
    ldst[k] = (unsigned short)d;
    loffA[k] = (unsigned short)atomicAdd(&histA[d >> 4], 1);  // int: native ds_add
    loffB[k] = (unsigned short)atomicAdd(&histB[s >> 4], 1);
  }
  __syncthreads();
  if (tid < kNumBins) {
    baseA[tid] = atomicAdd(&cursA[tid], histA[tid]);
    baseB[tid] = atomicAdd(&cursB[tid], histB[tid]);
  }
  __syncthreads();
  for (int k = tid; k < nloc; k += 256) {
    float wv = w[e0 + k];
    unsigned wu = __float_as_uint(wv);
    int s = lsrc[k], d = ldst[k];
    int binA = d >> 4, posA = baseA[binA] + loffA[k];
    if (posA < kCap)
      binsA[(size_t)binA * kCap + posA] = make_uint2(((unsigned)s << 8) | (d & 15), wu);
    int binB = s >> 4, posB = baseB[binB] + loffB[k];
    if (posB < kCap)
      binsB[(size_t)binB * kCap + posB] = make_uint2(((unsigned)d << 8) | (s & 15), wu);
  }
}

// K2' (fallback, single bin array): same as above for one key direction.
__global__ void __launch_bounds__(256) k_bin(
    const int* __restrict__ key, const int* __restrict__ other,
    const float* __restrict__ w, uint2* __restrict__ bins,
    int* __restrict__ cursors, int E) {
  __shared__ int hist[kNumBins], base[kNumBins];
  __shared__ unsigned short lkey[kChunk], loth[kChunk], loff[kChunk];
  int tid = threadIdx.x;
  int e0 = blockIdx.x * kChunk;
  int nloc = min(kChunk, E - e0);
  if (tid < kNumBins) hist[tid] = 0;
  __syncthreads();
  for (int k = tid; k < nloc; k += 256) {
    int kk = key[e0 + k];
    lkey[k] = (unsigned short)kk;
    loth[k] = (unsigned short)other[e0 + k];
    loff[k] = (unsigned short)atomicAdd(&hist[kk >> 4], 1);
  }
  __syncthreads();
  if (tid < kNumBins) base[tid] = atomicAdd(&cursors[tid], hist[tid]);
  __syncthreads();
  for (int k = tid; k < nloc; k += 256) {
    int kk = lkey[k];
    int bin = kk >> 4;
    int pos = base[bin] + loff[k];
    if (pos < kCap)
      bins[(size_t)bin * kCap + pos] =
          make_uint2(((unsigned)loth[k] << 8) | (kk & 15), __float_as_uint(w[e0 + k]));
  }
}

// K3/K4: one block owns one tile. Private per-half-wave LDS replicas (no
// atomics), then 32-way tree-sum. mode 0: out=mu, eps_t=x_t-mu. mode 1: out=dx.
__global__ void __launch_bounds__(1024) k_accum(
    const uint2* __restrict__ bins, const int* __restrict__ cursors,
    const float* __restrict__ vals, const float* __restrict__ x_t,
    const float* __restrict__ fx_t, float* __restrict__ eps_t,
    float* __restrict__ out, int N, int mode) {
  __shared__ float acc[32][kTileNodes * kB];   // [slot][local*32+b] = 64 KB
  int tid = threadIdx.x;
  int b = tid & 31;
  int slot = tid >> 5;                         // 32 half-wave slots
  float* my = acc[slot];
#pragma unroll
  for (int l = 0; l < kTileNodes; l++) my[l * kB + b] = 0.0f;  // private: no barrier
  int t = blockIdx.x;
  int count = min(cursors[t], kCap);
  const uint2* bp = bins + (size_t)t * kCap;
  int i = slot;
  uint2 r = (i < count) ? bp[i] : make_uint2(0u, 0u);
  while (i < count) {                          // 1-deep record prefetch
    int inext = i + 32;
    uint2 rn = (inext < count) ? bp[inext] : make_uint2(0u, 0u);
    float v = vals[((r.x >> 8) << kLogB) + b]; // 128B line per half-wave (L2)
    my[(r.x & 255) * kB + b] += __uint_as_float(r.y) * v;  // bank ≡ b: conflict-free
    r = rn;
    i = inext;
  }
  __syncthreads();
  int n0 = t * kTileNodes;
  for (int k = tid; k < kTileNodes * kB; k += 1024) {   // 512 outputs
    int local = k >> 5, bb = k & 31;
    float s = 0.0f;
#pragma unroll
    for (int sl = 0; sl < 32; sl++) s += acc[sl][local * kB + bb];  // 2-way: free
    int n = n0 + local;
    int j = n * kB + bb;
    if (mode == 0) {
      eps_t[j] = x_t[j] - s;
      out[bb * N + n] = s;                     // mu
    } else {
      float fx = fx_t[j];
      out[bb * N + n] = fmaf(1.0f - fx * fx, s, -eps_t[j]);  // dx
    }
  }
}

extern "C" void kernel_launch(void* const* d_in, const int* in_sizes, int n_in,
                              void* d_out, int out_size, void* d_ws, size_t ws_size,
                              hipStream_t stream) {
  const float* x    = (const float*)d_in[0];
  const float* w    = (const float*)d_in[1];
  const int*   esrc = (const int*)d_in[2];
  const int*   edst = (const int*)d_in[3];

  const int BN = in_sizes[0];          // 131072
  const int E  = in_sizes[1];          // 524288
  const int N  = BN / kB;              // 4096

  float* ws    = (float*)d_ws;
  float* x_t   = ws;                   // [BN]
  float* fx_t  = ws + (size_t)BN;      // [BN]
  float* eps_t = ws + 2 * (size_t)BN;  // [BN]
  int*   cursA = (int*)(ws + 3 * (size_t)BN);
  int*   cursB = cursA + kNumBins;
  uint2* binsA = (uint2*)(cursB + kNumBins);          // 5.25 MB
  uint2* binsB = binsA + (size_t)kNumBins * kCap;     // 5.25 MB (dual path)

  float* out_mu = (float*)d_out;
  float* out_dx = (float*)d_out + BN;

  const size_t need_dual = (3 * (size_t)BN + 2 * kNumBins) * 4 +
                           2 * (size_t)kNumBins * kCap * 8;
  int nblk_bin = (E + kChunk - 1) / kChunk;            // 256

  k_init<<<N / 64, 256, 0, stream>>>(x, x_t, fx_t, cursA, cursB, N);
  if (ws_size >= need_dual) {
    k_bin_dual<<<nblk_bin, 256, 0, stream>>>(esrc, edst, w, binsA, binsB,
                                             cursA, cursB, E);
    k_accum<<<kNumBins, 1024, 0, stream>>>(binsA, cursA, fx_t, x_t, fx_t,
                                           eps_t, out_mu, N, 0);
    k_accum<<<kNumBins, 1024, 0, stream>>>(binsB, cursB, eps_t, x_t, fx_t,
                                           eps_t, out_dx, N, 1);
  } else {                                             // single-bins fallback
    k_bin<<<nblk_bin, 256, 0, stream>>>(edst, esrc, w, binsA, cursA, E);
    k_accum<<<kNumBins, 1024, 0, stream>>>(binsA, cursA, fx_t, x_t, fx_t,
                                           eps_t, out_mu, N, 0);
    k_bin<<<nblk_bin, 256, 0, stream>>>(esrc, edst, w, binsA, cursB, E);
    k_accum<<<kNumBins, 1024, 0, stream>>>(binsA, cursB, eps_t, x_t, fx_t,
                                           eps_t, out_dx, N, 1);
  }
}

// Round 4
// 120.080 us; speedup vs baseline: 2.2607x; 1.2154x over previous
//
#include <hip/hip_runtime.h>

// Predictive-coding graph message passing, MI355X — round 4.
// R3 -> R4: (1) 512 bins of 8 nodes (was 256x16): grid 512 blocks = 2/CU =
// 100% occupancy (R3 was 1 block/CU = 50%); (2) software-pipelined gather
// (value prefetched one iteration ahead — R3 exposed ~200cyc L2 latency per
// record); (3) accum epilogues write node-major (coalesced), new k_final does
// the LDS-tiled de-transpose (R3 epilogue stores were 64 txn/wave).

static constexpr int kB = 32, kLogB = 5;
static constexpr int kTileNodes = 8;    // nodes per tile/bin
static constexpr int kNumBins = 512;    // N / kTileNodes (N = 4096)
static constexpr int kCap = 1408;       // slots/bin: mean 1024, +12 sigma slack
static constexpr int kChunk = 2048;     // edges per binning block

// K1: LDS-tiled transpose x[b*N+n] -> x_t[n*32+b]; fx_t = tanh(x); zero cursors.
__global__ void __launch_bounds__(256) k_init(
    const float* __restrict__ x, float* __restrict__ x_t,
    float* __restrict__ fx_t, int* __restrict__ cursA, int* __restrict__ cursB,
    int N) {
  __shared__ float tile[32][65];
  int tid = threadIdx.x;
  int n0 = blockIdx.x * 64;
  if (blockIdx.x == 0) {
    for (int t = tid; t < kNumBins; t += 256) { cursA[t] = 0; cursB[t] = 0; }
  }
  for (int k = tid; k < 32 * 64; k += 256) {
    int b = k >> 6, n = k & 63;
    tile[b][n] = x[b * N + n0 + n];
  }
  __syncthreads();
  for (int k = tid; k < 64 * 32; k += 256) {
    int n = k >> 5, b = k & 31;
    float xv = tile[b][n];
    int j = (n0 + n) * kB + b;
    x_t[j] = xv;
    fx_t[j] = tanhf(xv);
  }
}

// K2 (dual): one read of (esrc, edst, w); route into binsA (keyed by dst,
// payload src) and binsB (keyed by src, payload dst). Record = {meta,w},
// meta = (other<<8) | (key & 7).
__global__ void __launch_bounds__(256) k_bin_dual(
    const int* __restrict__ esrc, const int* __restrict__ edst,
    const float* __restrict__ w, uint2* __restrict__ binsA,
    uint2* __restrict__ binsB, int* __restrict__ cursA,
    int* __restrict__ cursB, int E) {
  __shared__ int histA[kNumBins], histB[kNumBins];
  __shared__ int baseA[kNumBins], baseB[kNumBins];
  __shared__ unsigned short lsrc[kChunk], ldst[kChunk];
  __shared__ unsigned short loffA[kChunk], loffB[kChunk];
  int tid = threadIdx.x;
  int e0 = blockIdx.x * kChunk;
  int nloc = min(kChunk, E - e0);
  for (int t = tid; t < kNumBins; t += 256) { histA[t] = 0; histB[t] = 0; }
  __syncthreads();
  for (int k = tid; k < nloc; k += 256) {
    int s = esrc[e0 + k], d = edst[e0 + k];
    lsrc[k] = (unsigned short)s;
    ldst[k] = (unsigned short)d;
    loffA[k] = (unsigned short)atomicAdd(&histA[d >> 3], 1);  // int: native ds_add
    loffB[k] = (unsigned short)atomicAdd(&histB[s >> 3], 1);
  }
  __syncthreads();
  for (int t = tid; t < kNumBins; t += 256) {
    baseA[t] = atomicAdd(&cursA[t], histA[t]);
    baseB[t] = atomicAdd(&cursB[t], histB[t]);
  }
  __syncthreads();
  for (int k = tid; k < nloc; k += 256) {
    float wv = w[e0 + k];
    unsigned wu = __float_as_uint(wv);
    int s = lsrc[k], d = ldst[k];
    int binA = d >> 3, posA = baseA[binA] + loffA[k];
    if (posA < kCap)
      binsA[(size_t)binA * kCap + posA] = make_uint2(((unsigned)s << 8) | (d & 7), wu);
    int binB = s >> 3, posB = baseB[binB] + loffB[k];
    if (posB < kCap)
      binsB[(size_t)binB * kCap + posB] = make_uint2(((unsigned)d << 8) | (s & 7), wu);
  }
}

// K3/K4: one block owns one 8-node tile. Private per-half-wave LDS replicas
// (no atomics), value gather software-pipelined 1 iteration ahead, then
// 32-way tree-sum. Epilogue writes are node-major (coalesced).
// mode 0: mu_t = s, eps_t = x_t - s.   mode 1: dx_t = -eps_t + (1-fx^2)*s.
__global__ void __launch_bounds__(1024) k_accum(
    const uint2* __restrict__ bins, const int* __restrict__ cursors,
    const float* __restrict__ vals, const float* __restrict__ x_t,
    const float* __restrict__ fx_t, const float* __restrict__ eps_in,
    float* __restrict__ o1, float* __restrict__ o2, int mode) {
  __shared__ float acc[32][kTileNodes * kB];   // [slot][local*32+b] = 32 KB
  int tid = threadIdx.x;
  int b = tid & 31;
  int slot = tid >> 5;                         // 32 half-wave slots
  float* my = acc[slot];
#pragma unroll
  for (int l = 0; l < kTileNodes; l++) my[l * kB + b] = 0.0f;  // private region
  int t = blockIdx.x;
  int cnt = min(cursors[t], kCap);
  const uint2* bp = bins + (size_t)t * kCap;

  int i = slot;
  uint2 r0 = (i < cnt) ? bp[i] : make_uint2(0u, 0u);
  uint2 r1 = (i + 32 < cnt) ? bp[i + 32] : make_uint2(0u, 0u);
  float v0 = (i < cnt) ? vals[((r0.x >> 8) << kLogB) + b] : 0.0f;
  while (i < cnt) {
    uint2 r2 = (i + 64 < cnt) ? bp[i + 64] : make_uint2(0u, 0u);
    float v1 = (i + 32 < cnt) ? vals[((r1.x >> 8) << kLogB) + b] : 0.0f;
    my[(r0.x & 7) * kB + b] += __uint_as_float(r0.y) * v0;  // bank ≡ b: free
    r0 = r1; r1 = r2; v0 = v1;
    i += 32;
  }
  __syncthreads();
  if (tid < kTileNodes * kB) {                 // 256 outputs
    int local = tid >> 5, bb = tid & 31;
    float s = 0.0f;
#pragma unroll
    for (int sl = 0; sl < 32; sl++) s += acc[sl][local * kB + bb];
    int j = (t * kTileNodes + local) * kB + bb;   // node-major: coalesced
    if (mode == 0) {
      o1[j] = s;                               // mu_t
      o2[j] = x_t[j] - s;                      // eps_t
    } else {
      float fx = fx_t[j];
      o1[j] = fmaf(1.0f - fx * fx, s, -eps_in[j]);  // dx_t
    }
  }
}

// K5: LDS-tiled de-transpose [N][32] -> [32][N] for both outputs.
// gridDim.x = 2 * N/64; y-half selects mu vs dx.
__global__ void __launch_bounds__(256) k_final(
    const float* __restrict__ mu_t, const float* __restrict__ dx_t,
    float* __restrict__ out_mu, float* __restrict__ out_dx, int N) {
  __shared__ float tile[64][33];
  int tid = threadIdx.x;
  int nblk = N >> 6;
  int which = blockIdx.x / nblk;
  int n0 = (blockIdx.x % nblk) * 64;
  const float* src = which ? dx_t : mu_t;
  float* dst = which ? out_dx : out_mu;
  for (int k = tid; k < 64 * 32; k += 256) {   // read coalesced (b fast)
    int n = k >> 5, b = k & 31;
    tile[n][b] = src[(n0 + n) * kB + b];
  }
  __syncthreads();
  for (int k = tid; k < 32 * 64; k += 256) {   // write coalesced (n fast)
    int b = k >> 6, n = k & 63;
    dst[b * N + n0 + n] = tile[n][b];
  }
}

extern "C" void kernel_launch(void* const* d_in, const int* in_sizes, int n_in,
                              void* d_out, int out_size, void* d_ws, size_t ws_size,
                              hipStream_t stream) {
  const float* x    = (const float*)d_in[0];
  const float* w    = (const float*)d_in[1];
  const int*   esrc = (const int*)d_in[2];
  const int*   edst = (const int*)d_in[3];

  const int BN = in_sizes[0];          // 131072
  const int E  = in_sizes[1];          // 524288
  const int N  = BN / kB;              // 4096

  float* ws    = (float*)d_ws;
  float* x_t   = ws;                   // [BN]
  float* fx_t  = ws + (size_t)BN;      // [BN]
  float* eps_t = ws + 2 * (size_t)BN;  // [BN]
  float* mu_t  = ws + 3 * (size_t)BN;  // [BN]
  float* dx_t  = ws + 4 * (size_t)BN;  // [BN]
  int*   cursA = (int*)(ws + 5 * (size_t)BN);
  int*   cursB = cursA + kNumBins;
  uint2* binsA = (uint2*)(cursB + kNumBins);          // 5.77 MB
  uint2* binsB = binsA + (size_t)kNumBins * kCap;     // 5.77 MB

  float* out_mu = (float*)d_out;
  float* out_dx = (float*)d_out + BN;

  int nblk_bin = (E + kChunk - 1) / kChunk;            // 256

  k_init<<<N / 64, 256, 0, stream>>>(x, x_t, fx_t, cursA, cursB, N);
  k_bin_dual<<<nblk_bin, 256, 0, stream>>>(esrc, edst, w, binsA, binsB,
                                           cursA, cursB, E);
  // Pass 1: mu[dst] += w * fx[src]
  k_accum<<<kNumBins, 1024, 0, stream>>>(binsA, cursA, fx_t, x_t, fx_t, fx_t,
                                         mu_t, eps_t, 0);
  // Pass 2: dxacc[src] += w * eps[dst]
  k_accum<<<kNumBins, 1024, 0, stream>>>(binsB, cursB, eps_t, x_t, fx_t, eps_t,
                                         dx_t, dx_t, 1);
  k_final<<<2 * (N / 64), 256, 0, stream>>>(mu_t, dx_t, out_mu, out_dx, N);
}

// Round 5
// 116.403 us; speedup vs baseline: 2.3321x; 1.0316x over previous
//
#include <hip/hip_runtime.h>

// Predictive-coding graph message passing, MI355X — round 5.
// R4 -> R5: (1) k_bin_dual at 1024 thr/block (16 waves/CU vs 4 — R4 ran at
// 12.5% occupancy with all HBM/LDS-atomic latency exposed), edge data in
// registers; (2) k_accum gather pipelined 2-deep (records 3-deep), replica
// rows padded to stride 33 (conflict-free epilogue); (3) outputs written
// directly from accum epilogue in 32B runs — k_final and mu_t/dx_t removed;
// (4) cursors zeroed via hipMemsetAsync.

static constexpr int kB = 32, kLogB = 5;
static constexpr int kTileNodes = 8;     // nodes per tile/bin
static constexpr int kNumBins = 512;     // N / kTileNodes (N = 4096)
static constexpr int kCap = 1408;        // slots/bin: mean 1024, +12 sigma
static constexpr int kChunk = 2048;      // edges per binning block
static constexpr int kRowPad = 33;       // padded row stride in accum replica

// K1: LDS-tiled transpose x[b*N+n] -> x_t[n*32+b]; fx_t = tanh(x).
__global__ void __launch_bounds__(256) k_init(
    const float* __restrict__ x, float* __restrict__ x_t,
    float* __restrict__ fx_t, int N) {
  __shared__ float tile[32][65];
  int tid = threadIdx.x;
  int n0 = blockIdx.x * 64;
  for (int k = tid; k < 32 * 64; k += 256) {
    int b = k >> 6, n = k & 63;
    tile[b][n] = x[b * N + n0 + n];
  }
  __syncthreads();
  for (int k = tid; k < 64 * 32; k += 256) {
    int n = k >> 5, b = k & 31;
    float xv = tile[b][n];
    int j = (n0 + n) * kB + b;
    x_t[j] = xv;
    fx_t[j] = tanhf(xv);
  }
}

// K2: one read of (esrc, edst, w); route into binsA (keyed by dst, payload
// src) and binsB (keyed by src, payload dst). Record = {meta, w},
// meta = (other<<8) | (key & 7). 1024 threads, 2 edges/thread, regs only.
__global__ void __launch_bounds__(1024) k_bin_dual(
    const int* __restrict__ esrc, const int* __restrict__ edst,
    const float* __restrict__ w, uint2* __restrict__ binsA,
    uint2* __restrict__ binsB, int* __restrict__ cursA,
    int* __restrict__ cursB, int E) {
  __shared__ int histA[kNumBins], histB[kNumBins];
  __shared__ int baseA[kNumBins], baseB[kNumBins];
  int tid = threadIdx.x;
  int e0 = blockIdx.x * kChunk;
  int nloc = min(kChunk, E - e0);
  if (tid < kNumBins) { histA[tid] = 0; histB[tid] = 0; }
  __syncthreads();
  // kChunk == 2*blockDim: two edges per thread, kept in registers.
  int k0 = tid, k1 = tid + 1024;
  int s0 = 0, d0 = 0, s1 = 0, d1 = 0;
  unsigned lA0 = 0, lB0 = 0, lA1 = 0, lB1 = 0;
  bool has0 = k0 < nloc, has1 = k1 < nloc;
  if (has0) {
    s0 = esrc[e0 + k0]; d0 = edst[e0 + k0];
    lA0 = atomicAdd(&histA[d0 >> 3], 1);   // int LDS atomic: native ds_add
    lB0 = atomicAdd(&histB[s0 >> 3], 1);
  }
  if (has1) {
    s1 = esrc[e0 + k1]; d1 = edst[e0 + k1];
    lA1 = atomicAdd(&histA[d1 >> 3], 1);
    lB1 = atomicAdd(&histB[s1 >> 3], 1);
  }
  __syncthreads();
  if (tid < kNumBins) {
    baseA[tid] = atomicAdd(&cursA[tid], histA[tid]);
    baseB[tid] = atomicAdd(&cursB[tid], histB[tid]);
  }
  __syncthreads();
  if (has0) {
    unsigned wu = __float_as_uint(w[e0 + k0]);
    int binA = d0 >> 3; int posA = baseA[binA] + (int)lA0;
    if (posA < kCap)
      binsA[(size_t)binA * kCap + posA] = make_uint2(((unsigned)s0 << 8) | (d0 & 7), wu);
    int binB = s0 >> 3; int posB = baseB[binB] + (int)lB0;
    if (posB < kCap)
      binsB[(size_t)binB * kCap + posB] = make_uint2(((unsigned)d0 << 8) | (s0 & 7), wu);
  }
  if (has1) {
    unsigned wu = __float_as_uint(w[e0 + k1]);
    int binA = d1 >> 3; int posA = baseA[binA] + (int)lA1;
    if (posA < kCap)
      binsA[(size_t)binA * kCap + posA] = make_uint2(((unsigned)s1 << 8) | (d1 & 7), wu);
    int binB = s1 >> 3; int posB = baseB[binB] + (int)lB1;
    if (posB < kCap)
      binsB[(size_t)binB * kCap + posB] = make_uint2(((unsigned)d1 << 8) | (s1 & 7), wu);
  }
}

// K3/K4: one block owns one 8-node tile. Private per-half-wave LDS replicas
// (no atomics), value gather pipelined 2 deep, records 3 deep; 32-way
// tree-sum epilogue writes outputs DIRECTLY in batch-major (8x32B runs/wave).
// mode 0: out = mu, eps_t = x_t - mu.   mode 1: out = dx.
__global__ void __launch_bounds__(1024) k_accum(
    const uint2* __restrict__ bins, const int* __restrict__ cursors,
    const float* __restrict__ vals, const float* __restrict__ x_t,
    const float* __restrict__ fx_t, float* __restrict__ eps_t,
    float* __restrict__ out, int N, int mode) {
  __shared__ float acc[32][kTileNodes * kRowPad];   // 33 KB, stride-33 rows
  int tid = threadIdx.x;
  int b = tid & 31;
  int slot = tid >> 5;                              // 32 half-wave slots
  float* my = acc[slot];
#pragma unroll
  for (int l = 0; l < kTileNodes; l++) my[l * kRowPad + b] = 0.0f;  // private
  int t = blockIdx.x;
  int cnt = min(cursors[t], kCap);
  const uint2* bp = bins + (size_t)t * kCap;

  int i = slot;
  uint2 r0 = (i      < cnt) ? bp[i]      : make_uint2(0u, 0u);
  uint2 r1 = (i + 32 < cnt) ? bp[i + 32] : make_uint2(0u, 0u);
  uint2 r2 = (i + 64 < cnt) ? bp[i + 64] : make_uint2(0u, 0u);
  float v0 = (i      < cnt) ? vals[((r0.x >> 8) << kLogB) + b] : 0.0f;
  float v1 = (i + 32 < cnt) ? vals[((r1.x >> 8) << kLogB) + b] : 0.0f;
  while (i < cnt) {
    uint2 r3 = (i + 96 < cnt) ? bp[i + 96] : make_uint2(0u, 0u);
    float v2 = (i + 64 < cnt) ? vals[((r2.x >> 8) << kLogB) + b] : 0.0f;
    my[(r0.x & 7) * kRowPad + b] += __uint_as_float(r0.y) * v0;  // conflict-free
    r0 = r1; r1 = r2; r2 = r3; v0 = v1; v1 = v2;
    i += 32;
  }
  __syncthreads();
  if (tid < kTileNodes * kB) {                      // 256 lanes
    int local = tid & 7, bb = tid >> 3;             // local-fast: 32B runs
    float s = 0.0f;
#pragma unroll
    for (int sl = 0; sl < 32; sl++) s += acc[sl][local * kRowPad + bb];
    int n = t * kTileNodes + local;
    int j = n * kB + bb;                            // node-major index
    if (mode == 0) {
      out[bb * N + n] = s;                          // mu (batch-major, 32B run)
      eps_t[j] = x_t[j] - s;
    } else {
      float fx = fx_t[j];
      out[bb * N + n] = fmaf(1.0f - fx * fx, s, -eps_t[j]);   // dx
    }
  }
}

extern "C" void kernel_launch(void* const* d_in, const int* in_sizes, int n_in,
                              void* d_out, int out_size, void* d_ws, size_t ws_size,
                              hipStream_t stream) {
  const float* x    = (const float*)d_in[0];
  const float* w    = (const float*)d_in[1];
  const int*   esrc = (const int*)d_in[2];
  const int*   edst = (const int*)d_in[3];

  const int BN = in_sizes[0];          // 131072
  const int E  = in_sizes[1];          // 524288
  const int N  = BN / kB;              // 4096

  float* ws    = (float*)d_ws;
  float* x_t   = ws;                   // [BN]
  float* fx_t  = ws + (size_t)BN;      // [BN]
  float* eps_t = ws + 2 * (size_t)BN;  // [BN]
  int*   cursA = (int*)(ws + 3 * (size_t)BN);
  int*   cursB = cursA + kNumBins;
  uint2* binsA = (uint2*)(cursB + kNumBins);          // 5.77 MB
  uint2* binsB = binsA + (size_t)kNumBins * kCap;     // 5.77 MB

  float* out_mu = (float*)d_out;
  float* out_dx = (float*)d_out + BN;

  int nblk_bin = (E + kChunk - 1) / kChunk;            // 256

  hipMemsetAsync(cursA, 0, 2 * kNumBins * sizeof(int), stream);
  k_init<<<N / 64, 256, 0, stream>>>(x, x_t, fx_t, N);
  k_bin_dual<<<nblk_bin, 1024, 0, stream>>>(esrc, edst, w, binsA, binsB,
                                            cursA, cursB, E);
  // Pass 1: mu[dst] += w * fx[src]
  k_accum<<<kNumBins, 1024, 0, stream>>>(binsA, cursA, fx_t, x_t, fx_t,
                                         eps_t, out_mu, N, 0);
  // Pass 2: dxacc[src] += w * eps[dst]
  k_accum<<<kNumBins, 1024, 0, stream>>>(binsB, cursB, eps_t, x_t, fx_t,
                                         eps_t, out_dx, N, 1);
}